// Round 4
// baseline (16823.628 us; speedup 1.0000x reference)
//
#include <hip/hip_runtime.h>

#define N_PTS   16384
#define M_PTS   4096
#define NS      16
#define C_IN    64
#define C_FEAT  67      // 3 + 64
#define C_OUT   128
#define QPB     8
#define GEMM_BLOCKS (M_PTS / QPB)   // 512
#define N_O_POS (M_PTS*3 + M_PTS*C_OUT)   // 536576

#define FPS_T   512
#define PPT     32      // points per thread; state ~200 VGPR, cap 256 via launch_bounds(512,2)

// ---------------------------------------------------------------------------
// Morton code + single-workgroup bitonic sort (runs once, ~60us).
// key = (morton18 << 14) | orig_idx
// ---------------------------------------------------------------------------
__device__ __forceinline__ unsigned spread3(unsigned x)
{
    x = (x | (x << 16)) & 0x030000FFu;
    x = (x | (x << 8))  & 0x0300F00Fu;
    x = (x | (x << 4))  & 0x030C30C3u;
    x = (x | (x << 2))  & 0x09249249u;
    return x;
}

__global__ __launch_bounds__(1024)
void morton_sort_kernel(const float* __restrict__ p, unsigned* __restrict__ keys)
{
    __shared__ unsigned k_lds[N_PTS];
    const int t = threadIdx.x;
#pragma unroll
    for (int s = 0; s < 16; ++s) {
        const int i = t + (s << 10);
        const float xx = p[3*i+0], yy = p[3*i+1], zz = p[3*i+2];
        unsigned cx = (unsigned)fminf(fmaxf(xx * 6.4f, 0.f), 63.f);
        unsigned cy = (unsigned)fminf(fmaxf(yy * 6.4f, 0.f), 63.f);
        unsigned cz = (unsigned)fminf(fmaxf(zz * 6.4f, 0.f), 63.f);
        const unsigned code = spread3(cx) | (spread3(cy) << 1) | (spread3(cz) << 2);
        k_lds[i] = (code << 14) | (unsigned)i;
    }
    __syncthreads();
    for (unsigned kk = 2; kk <= (unsigned)N_PTS; kk <<= 1) {
        for (unsigned jj = kk >> 1; jj >= 1; jj >>= 1) {
            for (int s = 0; s < 16; ++s) {
                const int i = t + (s << 10);
                const int ixj = i ^ (int)jj;
                if (ixj > i) {
                    const unsigned a = k_lds[i], b = k_lds[ixj];
                    const bool up = ((i & kk) == 0);
                    if (up ? (a > b) : (a < b)) { k_lds[i] = b; k_lds[ixj] = a; }
                }
            }
            __syncthreads();
        }
    }
#pragma unroll
    for (int s = 0; s < 16; ++s) {
        const int i = t + (s << 10);
        keys[i] = k_lds[i];
    }
}

// ---------------------------------------------------------------------------
// FPS: 512 threads x 32-point register bucket + bbox lower-bound pruning.
// launch_bounds(512,2): 8-wave block = 2 waves/SIMD -> 256-VGPR cap, no spill.
// Exact np semantics on computed distances ((dx^2+dy^2)+dz^2, no fma,
// contract off); pruned (bucket,query) pairs are provable no-ops:
//   d_ref(i,q) >= dlow >= mymax >= dist[i]  (dist only decreases).
// Argmax ties broken by smallest ORIGINAL index at every reduce level.
// ---------------------------------------------------------------------------
__global__ __launch_bounds__(FPS_T, 2)
void fps_kernel(const float* __restrict__ p, const unsigned* __restrict__ keys,
                int* __restrict__ fidx)
{
#pragma clang fp contract(off)
    const int t    = threadIdx.x;
    const int lane = t & 63;
    const int wid  = t >> 6;      // 0..7

    float px[PPT], py[PPT], pz[PPT], dist[PPT];
    int   oi[PPT];
    float lox =  3e38f, loy =  3e38f, loz =  3e38f;
    float hix = -3e38f, hiy = -3e38f, hiz = -3e38f;

#pragma unroll
    for (int k = 0; k < PPT; ++k) {
        const unsigned key = keys[t * PPT + k];
        const int j = (int)(key & 16383u);
        oi[k] = j;
        px[k] = p[3*j+0]; py[k] = p[3*j+1]; pz[k] = p[3*j+2];
        dist[k] = 1e10f;
        lox = fminf(lox, px[k]); hix = fmaxf(hix, px[k]);
        loy = fminf(loy, py[k]); hiy = fmaxf(hiy, py[k]);
        loz = fminf(loz, pz[k]); hiz = fmaxf(hiz, pz[k]);
    }

    __shared__ float  swv[8];
    __shared__ int    swi[8];
    __shared__ float4 sqv;

    if (t == 0) fidx[0] = 0;
#pragma unroll
    for (int k = 0; k < PPT; ++k)
        if (oi[k] == 0) sqv = make_float4(px[k], py[k], pz[k], 0.f);

    float mymax = 1e10f;  int myidx = -1;

    __syncthreads();

    for (int it = 1; it < M_PTS; ++it) {
        const float4 q4 = sqv;
        const float qx = q4.x, qy = q4.y, qz = q4.z;

        // bbox lower bound (1e-5 relative safety margin >> fp error ~4e-7)
        const float gx = fmaxf(fmaxf(lox - qx, qx - hix), 0.f);
        const float gy = fmaxf(fmaxf(loy - qy, qy - hiy), 0.f);
        const float gz = fmaxf(fmaxf(loz - qz, qz - hiz), 0.f);
        const float dlow = (gx*gx + gy*gy + gz*gz) * 0.99999f;

        const bool doflush = (dlow < mymax);
        if (doflush) {
            float bv = -1.f; int bi = 0x7fffffff;
#pragma unroll
            for (int k = 0; k < PPT; ++k) {
                const float dx = px[k] - qx;
                const float dy = py[k] - qy;
                const float dz = pz[k] - qz;
                float d = dx*dx + dy*dy;          // exact reference fp order
                d = d + dz*dz;
                const float nd = fminf(dist[k], d);
                dist[k] = nd;
                const bool tk = (nd > bv) || (nd == bv && oi[k] < bi);
                bv = tk ? nd : bv;  bi = tk ? oi[k] : bi;
            }
            mymax = bv; myidx = bi;
        }
        // wave-uniform: only re-reduce waves whose cached maxima changed;
        // swv[wid] from a previous iteration is still the exact wave max
        // when no lane flushed (dist/mymax untouched in that case).
        if (__ballot(doflush)) {
            float v = mymax; int ii = myidx;
#pragma unroll
            for (int off = 1; off < 64; off <<= 1) {
                const float ov = __shfl_xor(v, off, 64);
                const int   oo = __shfl_xor(ii, off, 64);
                const bool tk = (ov > v) || (ov == v && oo < ii);
                v = tk ? ov : v;  ii = tk ? oo : ii;
            }
            if (lane == 0) { swv[wid] = v; swi[wid] = ii; }
        }
        __syncthreads();

        // all threads: 8-entry LDS broadcast-read + register tree reduce
        float rv[8]; int ri[8];
#pragma unroll
        for (int w = 0; w < 8; ++w) { rv[w] = swv[w]; ri[w] = swi[w]; }
#pragma unroll
        for (int st = 4; st >= 1; st >>= 1) {
#pragma unroll
            for (int w = 0; w < 8; ++w) {
                if (w < st) {
                    const bool tk = (rv[w + st] > rv[w]) ||
                                    (rv[w + st] == rv[w] && ri[w + st] < ri[w]);
                    rv[w] = tk ? rv[w + st] : rv[w];
                    ri[w] = tk ? ri[w + st] : ri[w];
                }
            }
        }
        const int i2 = ri[0];

        if (myidx == i2) {               // unique owner (orig indices unique,
                                         // buckets disjoint)
            float ax = 0.f, ay = 0.f, az = 0.f;
#pragma unroll
            for (int k = 0; k < PPT; ++k) {
                const bool h = (oi[k] == i2);
                ax = h ? px[k] : ax; ay = h ? py[k] : ay; az = h ? pz[k] : az;
            }
            sqv = make_float4(ax, ay, az, 0.f);
            fidx[it] = i2;
            mymax = 3e38f;   // force self-flush next iter (winner's dist -> 0)
        }
        __syncthreads();
    }
}

// ---------------------------------------------------------------------------
// kNN: one wave per query; lane scans 256 coalesced candidates keeping an
// unsorted register top-16; 16-round shuffle extract-min merge.
// ---------------------------------------------------------------------------
__global__ __launch_bounds__(256)
void knn_kernel(const float* __restrict__ p, const int* __restrict__ fidx,
                int* __restrict__ knn_out, float* __restrict__ out_np)
{
    const int lane = threadIdx.x & 63;
    const int wid  = threadIdx.x >> 6;
    const int m    = blockIdx.x * 4 + wid;

    const int iq = fidx[m];
    const float qx = p[3*iq+0], qy = p[3*iq+1], qz = p[3*iq+2];
    if (lane == 0) { out_np[m*3+0] = qx; out_np[m*3+1] = qy; out_np[m*3+2] = qz; }

    float d16[16]; int i16[16];
#pragma unroll
    for (int jj = 0; jj < 16; ++jj) {
        const int j = jj*64 + lane;
        const float dx = p[3*j+0]-qx, dy = p[3*j+1]-qy, dz = p[3*j+2]-qz;
        d16[jj] = fmaf(dx, dx, fmaf(dy, dy, dz*dz));
        i16[jj] = j;
    }
    float wv = d16[0];
#pragma unroll
    for (int k = 1; k < 16; ++k) wv = fmaxf(wv, d16[k]);

    for (int jj = 16; jj < 256; ++jj) {
        const int j = jj*64 + lane;
        const float dx = p[3*j+0]-qx, dy = p[3*j+1]-qy, dz = p[3*j+2]-qz;
        const float d = fmaf(dx, dx, fmaf(dy, dy, dz*dz));
        if (d < wv) {
            bool done = false;
#pragma unroll
            for (int k = 0; k < 16; ++k) {
                const bool is = (!done) && (d16[k] == wv);
                d16[k] = is ? d : d16[k];
                i16[k] = is ? j : i16[k];
                done = done || is;
            }
            wv = d16[0];
#pragma unroll
            for (int k = 1; k < 16; ++k) wv = fmaxf(wv, d16[k]);
        }
    }

    float lmv; int lmi;
    {
        lmv = d16[0]; lmi = i16[0];
#pragma unroll
        for (int k = 1; k < 16; ++k) {
            const bool tk = (d16[k] < lmv) || (d16[k] == lmv && i16[k] < lmi);
            lmv = tk ? d16[k] : lmv;  lmi = tk ? i16[k] : lmi;
        }
    }
    int mykn = 0;
    for (int r = 0; r < 16; ++r) {
        float v = lmv; int ii = lmi;
#pragma unroll
        for (int off = 1; off < 64; off <<= 1) {
            const float ov = __shfl_xor(v, off, 64);
            const int   oo = __shfl_xor(ii, off, 64);
            const bool tk = (ov < v) || (ov == v && oo < ii);
            v = tk ? ov : v;  ii = tk ? oo : ii;
        }
        if (lane == r) mykn = ii;
        if (lmi == ii) {
#pragma unroll
            for (int k = 0; k < 16; ++k)
                d16[k] = (i16[k] == ii) ? 3.4e38f : d16[k];
            lmv = d16[0]; lmi = i16[0];
#pragma unroll
            for (int k = 1; k < 16; ++k) {
                const bool tk = (d16[k] < lmv) || (d16[k] == lmv && i16[k] < lmi);
                lmv = tk ? d16[k] : lmv;  lmi = tk ? i16[k] : lmi;
            }
        }
    }
    if (lane < 16) knn_out[m*16 + lane] = mykn;
}

// ---------------------------------------------------------------------------
// Gather + Linear (+stats | +BN/ReLU/maxpool).  PHASE 0: partial sums.
// PHASE 1: recompute y, apply scale/shift, relu, max over s, write out.
// ---------------------------------------------------------------------------
template <int PHASE>
__global__ __launch_bounds__(256)
void gemm_kernel(const float* __restrict__ p, const float* __restrict__ x,
                 const int* __restrict__ knn, const float* __restrict__ W,
                 const float* __restrict__ np_buf, float* __restrict__ part,
                 const float* __restrict__ scsh, float* __restrict__ out_y)
{
    __shared__ float w_lds[C_OUT * C_FEAT];
    __shared__ float feats[NS * 68];
    __shared__ float tmp[512];

    const int tid = threadIdx.x;
    for (int e = tid; e < C_OUT * C_FEAT; e += 256) w_lds[e] = W[e];
    __syncthreads();

    const int o  = tid & 127;
    const int s0 = (tid >> 7) * 8;
    float wreg[C_FEAT];
#pragma unroll
    for (int c = 0; c < C_FEAT; ++c) wreg[c] = w_lds[o * C_FEAT + c];

    float sc = 0.f, sh = 0.f;
    if (PHASE == 1) { sc = scsh[o]; sh = scsh[128 + o]; }

    float lsum = 0.f, lsq = 0.f;

    for (int ml = 0; ml < QPB; ++ml) {
        const int m = blockIdx.x * QPB + ml;
        __syncthreads();
        for (int e = tid; e < NS * C_FEAT; e += 256) {
            const int s = e / C_FEAT;
            const int c = e - s * C_FEAT;
            const int j = knn[m * NS + s];
            float v;
            if (c < 3) v = p[3*j + c] - np_buf[m*3 + c];
            else       v = x[j * C_IN + (c - 3)];
            feats[s * 68 + c] = v;
        }
        __syncthreads();

        float mx = 0.0f;
#pragma unroll
        for (int s8 = 0; s8 < 8; ++s8) {
            const int s = s0 + s8;
            const float4* fr = (const float4*)&feats[s * 68];
            float a = 0.f;
#pragma unroll
            for (int c4 = 0; c4 < 16; ++c4) {
                const float4 f = fr[c4];
                a = fmaf(f.x, wreg[c4*4+0], a);
                a = fmaf(f.y, wreg[c4*4+1], a);
                a = fmaf(f.z, wreg[c4*4+2], a);
                a = fmaf(f.w, wreg[c4*4+3], a);
            }
            a = fmaf(feats[s*68+64], wreg[64], a);
            a = fmaf(feats[s*68+65], wreg[65], a);
            a = fmaf(feats[s*68+66], wreg[66], a);
            if (PHASE == 0) { lsum += a; lsq = fmaf(a, a, lsq); }
            else {
                float v = fmaf(a, sc, sh);
                v = fmaxf(v, 0.f);
                mx = fmaxf(mx, v);
            }
        }
        if (PHASE == 1) {
            tmp[tid] = mx;
            __syncthreads();
            if (tid < 128) out_y[m * C_OUT + o] = fmaxf(tmp[tid], tmp[tid + 128]);
        }
    }

    if (PHASE == 0) {
        tmp[tid] = lsum; tmp[256 + tid] = lsq;
        __syncthreads();
        if (tid < 128) {
            part[blockIdx.x * 256 + o]       = tmp[tid] + tmp[tid + 128];
            part[blockIdx.x * 256 + 128 + o] = tmp[256 + tid] + tmp[256 + tid + 128];
        }
    }
}

// ---------------------------------------------------------------------------
__global__ __launch_bounds__(128)
void stats_kernel(const float* __restrict__ part, const float* __restrict__ gamma,
                  const float* __restrict__ beta, float* __restrict__ scsh,
                  float* __restrict__ out)
{
    const int o = threadIdx.x;
    float s = 0.f, s2 = 0.f;
    for (int b = 0; b < GEMM_BLOCKS; ++b) {
        s  += part[b * 256 + o];
        s2 += part[b * 256 + 128 + o];
    }
    const float inv  = 1.0f / 65536.0f;
    const float mean = s * inv;
    const float var  = fmaf(s2, inv, -mean * mean);
    const float sc   = gamma[o] * rsqrtf(var + 1e-5f);
    const float sh   = fmaf(-mean, sc, beta[o]);
    scsh[o] = sc; scsh[128 + o] = sh;
    if (o == 0) out[N_O_POS] = 4096.0f;   // n_o = N // STRIDE
}

// ---------------------------------------------------------------------------
extern "C" void kernel_launch(void* const* d_in, const int* in_sizes, int n_in,
                              void* d_out, int out_size, void* d_ws, size_t ws_size,
                              hipStream_t stream)
{
    const float* p     = (const float*)d_in[0];
    const float* x     = (const float*)d_in[1];
    const float* W     = (const float*)d_in[3];
    const float* gamma = (const float*)d_in[4];
    const float* beta  = (const float*)d_in[5];
    float* out = (float*)d_out;

    int*      fidx = (int*)d_ws;                       // 4096
    int*      knn  = fidx + M_PTS;                     // 4096*16
    float*    part = (float*)(knn + M_PTS * NS);       // 512*256
    float*    scsh = part + GEMM_BLOCKS * 256;         // 256
    unsigned* keys = (unsigned*)(scsh + 256);          // 16384

    float* out_np = out;                               // (M,3)
    float* out_y  = out + M_PTS * 3;                   // (M,128)

    morton_sort_kernel<<<dim3(1), dim3(1024), 0, stream>>>(p, keys);
    fps_kernel<<<dim3(1), dim3(FPS_T), 0, stream>>>(p, keys, fidx);
    knn_kernel<<<dim3(M_PTS / 4), dim3(256), 0, stream>>>(p, fidx, knn, out_np);
    gemm_kernel<0><<<dim3(GEMM_BLOCKS), dim3(256), 0, stream>>>(
        p, x, knn, W, out_np, part, scsh, out_y);
    stats_kernel<<<dim3(1), dim3(128), 0, stream>>>(part, gamma, beta, scsh, out);
    gemm_kernel<1><<<dim3(GEMM_BLOCKS), dim3(256), 0, stream>>>(
        p, x, knn, W, out_np, part, scsh, out_y);
}

// Round 6
// 11067.106 us; speedup vs baseline: 1.5201x; 1.5201x over previous
//
#include <hip/hip_runtime.h>

#define N_PTS   16384
#define M_PTS   4096
#define NS      16
#define C_IN    64
#define C_FEAT  67      // 3 + 64
#define C_OUT   128
#define QPB     8
#define GEMM_BLOCKS (M_PTS / QPB)   // 512
#define N_O_POS (M_PTS*3 + M_PTS*C_OUT)   // 536576

#define FPS_T   1024
#define PPT     16      // state ~100 VGPR; waves_per_eu(4,4) -> 128 budget, no spill

// ---------------------------------------------------------------------------
// Morton code + single-workgroup bitonic sort (runs once, ~60us).
// key = (morton18 << 14) | orig_idx
// ---------------------------------------------------------------------------
__device__ __forceinline__ unsigned spread3(unsigned x)
{
    x = (x | (x << 16)) & 0x030000FFu;
    x = (x | (x << 8))  & 0x0300F00Fu;
    x = (x | (x << 4))  & 0x030C30C3u;
    x = (x | (x << 2))  & 0x09249249u;
    return x;
}

__global__ __launch_bounds__(1024)
void morton_sort_kernel(const float* __restrict__ p, unsigned* __restrict__ keys)
{
    __shared__ unsigned k_lds[N_PTS];
    const int t = threadIdx.x;
#pragma unroll
    for (int s = 0; s < 16; ++s) {
        const int i = t + (s << 10);
        const float xx = p[3*i+0], yy = p[3*i+1], zz = p[3*i+2];
        unsigned cx = (unsigned)fminf(fmaxf(xx * 6.4f, 0.f), 63.f);
        unsigned cy = (unsigned)fminf(fmaxf(yy * 6.4f, 0.f), 63.f);
        unsigned cz = (unsigned)fminf(fmaxf(zz * 6.4f, 0.f), 63.f);
        const unsigned code = spread3(cx) | (spread3(cy) << 1) | (spread3(cz) << 2);
        k_lds[i] = (code << 14) | (unsigned)i;
    }
    __syncthreads();
    for (unsigned kk = 2; kk <= (unsigned)N_PTS; kk <<= 1) {
        for (unsigned jj = kk >> 1; jj >= 1; jj >>= 1) {
            for (int s = 0; s < 16; ++s) {
                const int i = t + (s << 10);
                const int ixj = i ^ (int)jj;
                if (ixj > i) {
                    const unsigned a = k_lds[i], b = k_lds[ixj];
                    const bool up = ((i & kk) == 0);
                    if (up ? (a > b) : (a < b)) { k_lds[i] = b; k_lds[ixj] = a; }
                }
            }
            __syncthreads();
        }
    }
#pragma unroll
    for (int s = 0; s < 16; ++s) {
        const int i = t + (s << 10);
        keys[i] = k_lds[i];
    }
}

// ---------------------------------------------------------------------------
// FPS: 1024 threads x 16-point register bucket + bbox lower-bound pruning.
// amdgpu_waves_per_eu(4,4): allocator budget = 512/4 = 128 VGPR, scheduler
// target = the 1024-thread block's structural floor -> no spill (need ~100),
// block remains launchable.
// Exact np semantics on computed distances ((dx^2+dy^2)+dz^2, no fma,
// contract off); pruned (bucket,query) pairs are provable no-ops:
//   d_ref(i,q) >= dlow >= mymax >= dist[i]  (dist only decreases).
// Argmax ties broken by smallest ORIGINAL index at every reduce level.
// ---------------------------------------------------------------------------
__attribute__((amdgpu_waves_per_eu(4, 4)))
__global__ __launch_bounds__(FPS_T)
void fps_kernel(const float* __restrict__ p, const unsigned* __restrict__ keys,
                int* __restrict__ fidx)
{
#pragma clang fp contract(off)
    const int t    = threadIdx.x;
    const int lane = t & 63;
    const int wid  = t >> 6;      // 0..15

    float px[PPT], py[PPT], pz[PPT], dist[PPT];
    int   oi[PPT];
    float lox =  3e38f, loy =  3e38f, loz =  3e38f;
    float hix = -3e38f, hiy = -3e38f, hiz = -3e38f;

#pragma unroll
    for (int k = 0; k < PPT; ++k) {
        const unsigned key = keys[t * PPT + k];
        const int j = (int)(key & 16383u);
        oi[k] = j;
        px[k] = p[3*j+0]; py[k] = p[3*j+1]; pz[k] = p[3*j+2];
        dist[k] = 1e10f;
        lox = fminf(lox, px[k]); hix = fmaxf(hix, px[k]);
        loy = fminf(loy, py[k]); hiy = fmaxf(hiy, py[k]);
        loz = fminf(loz, pz[k]); hiz = fmaxf(hiz, pz[k]);
    }

    __shared__ float  swv[16];
    __shared__ int    swi[16];
    __shared__ float4 sqv;

    if (t == 0) fidx[0] = 0;
#pragma unroll
    for (int k = 0; k < PPT; ++k)
        if (oi[k] == 0) sqv = make_float4(px[k], py[k], pz[k], 0.f);

    float mymax = 1e10f;  int myidx = -1;

    __syncthreads();

    for (int it = 1; it < M_PTS; ++it) {
        const float4 q4 = sqv;
        const float qx = q4.x, qy = q4.y, qz = q4.z;

        // bbox lower bound (1e-5 relative safety margin >> fp error ~4e-7)
        const float gx = fmaxf(fmaxf(lox - qx, qx - hix), 0.f);
        const float gy = fmaxf(fmaxf(loy - qy, qy - hiy), 0.f);
        const float gz = fmaxf(fmaxf(loz - qz, qz - hiz), 0.f);
        const float dlow = (gx*gx + gy*gy + gz*gz) * 0.99999f;

        const bool doflush = (dlow < mymax);
        if (doflush) {
            float bv = -1.f; int bi = 0x7fffffff;
#pragma unroll
            for (int k = 0; k < PPT; ++k) {
                const float dx = px[k] - qx;
                const float dy = py[k] - qy;
                const float dz = pz[k] - qz;
                float d = dx*dx + dy*dy;          // exact reference fp order
                d = d + dz*dz;
                const float nd = fminf(dist[k], d);
                dist[k] = nd;
                const bool tk = (nd > bv) || (nd == bv && oi[k] < bi);
                bv = tk ? nd : bv;  bi = tk ? oi[k] : bi;
            }
            mymax = bv; myidx = bi;
        }
        // wave-uniform: only re-reduce waves whose cached maxima changed;
        // swv[wid] from a previous iteration is still the exact wave max
        // when no lane flushed (dist/mymax untouched in that case).
        if (__ballot(doflush)) {
            float v = mymax; int ii = myidx;
#pragma unroll
            for (int off = 1; off < 64; off <<= 1) {
                const float ov = __shfl_xor(v, off, 64);
                const int   oo = __shfl_xor(ii, off, 64);
                const bool tk = (ov > v) || (ov == v && oo < ii);
                v = tk ? ov : v;  ii = tk ? oo : ii;
            }
            if (lane == 0) { swv[wid] = v; swi[wid] = ii; }
        }
        __syncthreads();

        // 16-entry broadcast read + 4-round shuffle reduce (all lanes converge)
        float v2 = swv[lane & 15];  int i2 = swi[lane & 15];
#pragma unroll
        for (int off = 1; off < 16; off <<= 1) {
            const float ov = __shfl_xor(v2, off, 64);
            const int   oo = __shfl_xor(i2, off, 64);
            const bool tk = (ov > v2) || (ov == v2 && oo < i2);
            v2 = tk ? ov : v2;  i2 = tk ? oo : i2;
        }

        if (myidx == i2) {               // unique owner (orig indices unique,
                                         // buckets disjoint)
            float ax = 0.f, ay = 0.f, az = 0.f;
#pragma unroll
            for (int k = 0; k < PPT; ++k) {
                const bool h = (oi[k] == i2);
                ax = h ? px[k] : ax; ay = h ? py[k] : ay; az = h ? pz[k] : az;
            }
            sqv = make_float4(ax, ay, az, 0.f);
            fidx[it] = i2;
            mymax = 3e38f;   // force self-flush next iter (winner's dist -> 0)
        }
        __syncthreads();
    }
}

// ---------------------------------------------------------------------------
// kNN: one wave per query; lane scans 256 coalesced candidates keeping an
// unsorted register top-16; 16-round shuffle extract-min merge.
// ---------------------------------------------------------------------------
__global__ __launch_bounds__(256)
void knn_kernel(const float* __restrict__ p, const int* __restrict__ fidx,
                int* __restrict__ knn_out, float* __restrict__ out_np)
{
    const int lane = threadIdx.x & 63;
    const int wid  = threadIdx.x >> 6;
    const int m    = blockIdx.x * 4 + wid;

    const int iq = fidx[m];
    const float qx = p[3*iq+0], qy = p[3*iq+1], qz = p[3*iq+2];
    if (lane == 0) { out_np[m*3+0] = qx; out_np[m*3+1] = qy; out_np[m*3+2] = qz; }

    float d16[16]; int i16[16];
#pragma unroll
    for (int jj = 0; jj < 16; ++jj) {
        const int j = jj*64 + lane;
        const float dx = p[3*j+0]-qx, dy = p[3*j+1]-qy, dz = p[3*j+2]-qz;
        d16[jj] = fmaf(dx, dx, fmaf(dy, dy, dz*dz));
        i16[jj] = j;
    }
    float wv = d16[0];
#pragma unroll
    for (int k = 1; k < 16; ++k) wv = fmaxf(wv, d16[k]);

    for (int jj = 16; jj < 256; ++jj) {
        const int j = jj*64 + lane;
        const float dx = p[3*j+0]-qx, dy = p[3*j+1]-qy, dz = p[3*j+2]-qz;
        const float d = fmaf(dx, dx, fmaf(dy, dy, dz*dz));
        if (d < wv) {
            bool done = false;
#pragma unroll
            for (int k = 0; k < 16; ++k) {
                const bool is = (!done) && (d16[k] == wv);
                d16[k] = is ? d : d16[k];
                i16[k] = is ? j : i16[k];
                done = done || is;
            }
            wv = d16[0];
#pragma unroll
            for (int k = 1; k < 16; ++k) wv = fmaxf(wv, d16[k]);
        }
    }

    float lmv; int lmi;
    {
        lmv = d16[0]; lmi = i16[0];
#pragma unroll
        for (int k = 1; k < 16; ++k) {
            const bool tk = (d16[k] < lmv) || (d16[k] == lmv && i16[k] < lmi);
            lmv = tk ? d16[k] : lmv;  lmi = tk ? i16[k] : lmi;
        }
    }
    int mykn = 0;
    for (int r = 0; r < 16; ++r) {
        float v = lmv; int ii = lmi;
#pragma unroll
        for (int off = 1; off < 64; off <<= 1) {
            const float ov = __shfl_xor(v, off, 64);
            const int   oo = __shfl_xor(ii, off, 64);
            const bool tk = (ov < v) || (ov == v && oo < ii);
            v = tk ? ov : v;  ii = tk ? oo : ii;
        }
        if (lane == r) mykn = ii;
        if (lmi == ii) {
#pragma unroll
            for (int k = 0; k < 16; ++k)
                d16[k] = (i16[k] == ii) ? 3.4e38f : d16[k];
            lmv = d16[0]; lmi = i16[0];
#pragma unroll
            for (int k = 1; k < 16; ++k) {
                const bool tk = (d16[k] < lmv) || (d16[k] == lmv && i16[k] < lmi);
                lmv = tk ? d16[k] : lmv;  lmi = tk ? i16[k] : lmi;
            }
        }
    }
    if (lane < 16) knn_out[m*16 + lane] = mykn;
}

// ---------------------------------------------------------------------------
// Gather + Linear (+stats | +BN/ReLU/maxpool).  PHASE 0: partial sums.
// PHASE 1: recompute y, apply scale/shift, relu, max over s, write out.
// ---------------------------------------------------------------------------
template <int PHASE>
__global__ __launch_bounds__(256)
void gemm_kernel(const float* __restrict__ p, const float* __restrict__ x,
                 const int* __restrict__ knn, const float* __restrict__ W,
                 const float* __restrict__ np_buf, float* __restrict__ part,
                 const float* __restrict__ scsh, float* __restrict__ out_y)
{
    __shared__ float w_lds[C_OUT * C_FEAT];
    __shared__ float feats[NS * 68];
    __shared__ float tmp[512];

    const int tid = threadIdx.x;
    for (int e = tid; e < C_OUT * C_FEAT; e += 256) w_lds[e] = W[e];
    __syncthreads();

    const int o  = tid & 127;
    const int s0 = (tid >> 7) * 8;
    float wreg[C_FEAT];
#pragma unroll
    for (int c = 0; c < C_FEAT; ++c) wreg[c] = w_lds[o * C_FEAT + c];

    float sc = 0.f, sh = 0.f;
    if (PHASE == 1) { sc = scsh[o]; sh = scsh[128 + o]; }

    float lsum = 0.f, lsq = 0.f;

    for (int ml = 0; ml < QPB; ++ml) {
        const int m = blockIdx.x * QPB + ml;
        __syncthreads();
        for (int e = tid; e < NS * C_FEAT; e += 256) {
            const int s = e / C_FEAT;
            const int c = e - s * C_FEAT;
            const int j = knn[m * NS + s];
            float v;
            if (c < 3) v = p[3*j + c] - np_buf[m*3 + c];
            else       v = x[j * C_IN + (c - 3)];
            feats[s * 68 + c] = v;
        }
        __syncthreads();

        float mx = 0.0f;
#pragma unroll
        for (int s8 = 0; s8 < 8; ++s8) {
            const int s = s0 + s8;
            const float4* fr = (const float4*)&feats[s * 68];
            float a = 0.f;
#pragma unroll
            for (int c4 = 0; c4 < 16; ++c4) {
                const float4 f = fr[c4];
                a = fmaf(f.x, wreg[c4*4+0], a);
                a = fmaf(f.y, wreg[c4*4+1], a);
                a = fmaf(f.z, wreg[c4*4+2], a);
                a = fmaf(f.w, wreg[c4*4+3], a);
            }
            a = fmaf(feats[s*68+64], wreg[64], a);
            a = fmaf(feats[s*68+65], wreg[65], a);
            a = fmaf(feats[s*68+66], wreg[66], a);
            if (PHASE == 0) { lsum += a; lsq = fmaf(a, a, lsq); }
            else {
                float v = fmaf(a, sc, sh);
                v = fmaxf(v, 0.f);
                mx = fmaxf(mx, v);
            }
        }
        if (PHASE == 1) {
            tmp[tid] = mx;
            __syncthreads();
            if (tid < 128) out_y[m * C_OUT + o] = fmaxf(tmp[tid], tmp[tid + 128]);
        }
    }

    if (PHASE == 0) {
        tmp[tid] = lsum; tmp[256 + tid] = lsq;
        __syncthreads();
        if (tid < 128) {
            part[blockIdx.x * 256 + o]       = tmp[tid] + tmp[tid + 128];
            part[blockIdx.x * 256 + 128 + o] = tmp[256 + tid] + tmp[256 + tid + 128];
        }
    }
}

// ---------------------------------------------------------------------------
__global__ __launch_bounds__(128)
void stats_kernel(const float* __restrict__ part, const float* __restrict__ gamma,
                  const float* __restrict__ beta, float* __restrict__ scsh,
                  float* __restrict__ out)
{
    const int o = threadIdx.x;
    float s = 0.f, s2 = 0.f;
    for (int b = 0; b < GEMM_BLOCKS; ++b) {
        s  += part[b * 256 + o];
        s2 += part[b * 256 + 128 + o];
    }
    const float inv  = 1.0f / 65536.0f;
    const float mean = s * inv;
    const float var  = fmaf(s2, inv, -mean * mean);
    const float sc   = gamma[o] * rsqrtf(var + 1e-5f);
    const float sh   = fmaf(-mean, sc, beta[o]);
    scsh[o] = sc; scsh[128 + o] = sh;
    if (o == 0) out[N_O_POS] = 4096.0f;   // n_o = N // STRIDE
}

// ---------------------------------------------------------------------------
extern "C" void kernel_launch(void* const* d_in, const int* in_sizes, int n_in,
                              void* d_out, int out_size, void* d_ws, size_t ws_size,
                              hipStream_t stream)
{
    const float* p     = (const float*)d_in[0];
    const float* x     = (const float*)d_in[1];
    const float* W     = (const float*)d_in[3];
    const float* gamma = (const float*)d_in[4];
    const float* beta  = (const float*)d_in[5];
    float* out = (float*)d_out;

    int*      fidx = (int*)d_ws;                       // 4096
    int*      knn  = fidx + M_PTS;                     // 4096*16
    float*    part = (float*)(knn + M_PTS * NS);       // 512*256
    float*    scsh = part + GEMM_BLOCKS * 256;         // 256
    unsigned* keys = (unsigned*)(scsh + 256);          // 16384

    float* out_np = out;                               // (M,3)
    float* out_y  = out + M_PTS * 3;                   // (M,128)

    morton_sort_kernel<<<dim3(1), dim3(1024), 0, stream>>>(p, keys);
    fps_kernel<<<dim3(1), dim3(FPS_T), 0, stream>>>(p, keys, fidx);
    knn_kernel<<<dim3(M_PTS / 4), dim3(256), 0, stream>>>(p, fidx, knn, out_np);
    gemm_kernel<0><<<dim3(GEMM_BLOCKS), dim3(256), 0, stream>>>(
        p, x, knn, W, out_np, part, scsh, out_y);
    stats_kernel<<<dim3(1), dim3(128), 0, stream>>>(part, gamma, beta, scsh, out);
    gemm_kernel<1><<<dim3(GEMM_BLOCKS), dim3(256), 0, stream>>>(
        p, x, knn, W, out_np, part, scsh, out_y);
}